// Round 11
// baseline (265.375 us; speedup 1.0000x reference)
//
#include <hip/hip_runtime.h>

// Causal attention fwd: B=2,H=16,L=2048,D=64 fp32 in/out, bf16 MFMA inside.
//  1) repack: fp32 K,V -> bf16 FRAGMENT-MAJOR images in d_ws (K'[chunk][kv],
//     V'[chunk][d]); a wave's MFMA fragments are coalesced dwordx4 loads.
//  2) fattn_fwd: barrier-free flash attention. Block = 32 q-rows; 4 waves
//     split KV 4-ways (strip = 32 kv, wave w owns strips s == w mod 4).
//     32x32x16 swapped-operand, in-register softmax.
//     R11: FULL RESIDENCY — launch_bounds(256,8) (VGPR<=64, measured 60),
//     LDS cut to 8.4KB (sequential 3-round merge) -> all 8 blocks/CU
//     resident, no drain. Scale+log2e folded into Q; no exp bias (the
//     2^C0 factor cancels in the final normalize) -> bare v_exp_f32.
// Workspace: 32bh * 32tiles * 16384B = 16.8MB.

constexpr int Lq = 2048;
constexpr int Dh = 64;
constexpr int TILEB = 16384;  // K' 8KB + V' 8KB per 64-kv tile
constexpr int VOFF  = 8192;

typedef __attribute__((ext_vector_type(16))) float f32x16;
typedef __attribute__((ext_vector_type(4))) float f32x4;
typedef __attribute__((ext_vector_type(8))) unsigned short u16x8;
typedef __attribute__((ext_vector_type(4))) unsigned int u32x4;
typedef __attribute__((ext_vector_type(8))) __bf16 bf16x8;

__device__ __forceinline__ unsigned short f2bf(float f) {
  __bf16 h = (__bf16)f;
  return __builtin_bit_cast(unsigned short, h);
}
__device__ __forceinline__ unsigned cvtpk(float lo, float hi) {
  unsigned r;
  asm("v_cvt_pk_bf16_f32 %0, %1, %2" : "=v"(r) : "v"(lo), "v"(hi));
  return r;
}
__device__ __forceinline__ f32x16 mfma32(u16x8 a, u16x8 b, f32x16 c) {
  return __builtin_amdgcn_mfma_f32_32x32x16_bf16(
      __builtin_bit_cast(bf16x8, a), __builtin_bit_cast(bf16x8, b), c, 0, 0, 0);
}
__device__ __forceinline__ void plswap(unsigned a, unsigned b,
                                       unsigned& wlo, unsigned& whi) {
#if __has_builtin(__builtin_amdgcn_permlane32_swap)
  auto r = __builtin_amdgcn_permlane32_swap((int)a, (int)b, false, false);
  wlo = (unsigned)r[0];
  whi = (unsigned)r[1];
#else
  const int hh = (threadIdx.x >> 5) & 1;
  unsigned pa = (unsigned)__shfl_xor((int)a, 32);
  unsigned pb = (unsigned)__shfl_xor((int)b, 32);
  wlo = hh ? pb : a;
  whi = hh ? b : pa;
#endif
}

// ---------------- prepass: fp32 K,V -> bf16 fragment-major images ----------------
__global__ __launch_bounds__(256, 2)
void repack(const float* __restrict__ K, const float* __restrict__ V,
            unsigned char* __restrict__ W) {
  __shared__ unsigned short Vl[64][72];

  const int tid = threadIdx.x;
  const int bt  = blockIdx.x;             // bh*32 + tile
  const int bh  = bt >> 5;
  const int tl  = bt & 31;
  const size_t src = (size_t)bh * Lq * Dh + (size_t)tl * 64 * Dh;
  unsigned char* img = W + (size_t)bt * TILEB;

  const int r  = tid >> 2;        // 0..63
  const int c2 = (tid & 3) * 2;   // chunk pair base

  {  // K': chunk c holds d in [8c,8c+8); K'[c][r] 16B at (c*64+r)*16
    const float* kp = K + src + (size_t)r * Dh + c2 * 8;
    f32x4 a = *(const f32x4*)kp;
    f32x4 b = *(const f32x4*)(kp + 4);
    f32x4 c = *(const f32x4*)(kp + 8);
    f32x4 d = *(const f32x4*)(kp + 12);
    u16x8 lo, hi;
    #pragma unroll
    for (int j = 0; j < 4; ++j) {
      lo[j] = f2bf(a[j]); lo[4 + j] = f2bf(b[j]);
      hi[j] = f2bf(c[j]); hi[4 + j] = f2bf(d[j]);
    }
    *(u16x8*)(img + (c2 * 64 + r) * 16)       = lo;
    *(u16x8*)(img + ((c2 + 1) * 64 + r) * 16) = hi;
  }
  {  // V staged to LDS row-major [kv][d]
    const float* vp = V + src + (size_t)r * Dh + c2 * 8;
    f32x4 a = *(const f32x4*)vp;
    f32x4 b = *(const f32x4*)(vp + 4);
    f32x4 c = *(const f32x4*)(vp + 8);
    f32x4 d = *(const f32x4*)(vp + 12);
    u16x8 lo, hi;
    #pragma unroll
    for (int j = 0; j < 4; ++j) {
      lo[j] = f2bf(a[j]); lo[4 + j] = f2bf(b[j]);
      hi[j] = f2bf(c[j]); hi[4 + j] = f2bf(d[j]);
    }
    *(u16x8*)&Vl[r][c2 * 8]     = lo;
    *(u16x8*)&Vl[r][c2 * 8 + 8] = hi;
  }
  __syncthreads();
  {  // V': chunk c holds kv in [8c,8c+8); V'[c][d] = V[8c+e][d]
    u16x8 lo, hi;
    #pragma unroll
    for (int e = 0; e < 8; ++e) {
      lo[e] = Vl[c2 * 8 + e][r];
      hi[e] = Vl[c2 * 8 + 8 + e][r];
    }
    *(u16x8*)(img + VOFF + (c2 * 64 + r) * 16)       = lo;
    *(u16x8*)(img + VOFF + ((c2 + 1) * 64 + r) * 16) = hi;
  }
}

// ---------------- main: barrier-free, KV-parallel waves, full residency ----------------
__global__ __launch_bounds__(256, 8)
void fattn_fwd(const float* __restrict__ Q, const unsigned char* __restrict__ W,
               float* __restrict__ O) {
  __shared__ float Mrg[64][33];   // one wave's partials per merge round

  const int tid  = threadIdx.x;
  const int lane = tid & 63;
  const int w    = tid >> 6;     // 0..3 = KV strip class (s == w mod 4)
  const int l31  = lane & 31;
  const int h    = lane >> 5;

  // Constant-per-CU heavy-first decode (R10-verified).
  const int bid = blockIdx.x;
  const int bh  = (bid & 7) * 4 + ((bid >> 3) & 3);   // XCD-grouped bh
  const int v_  = (bid >> 5) & 7;
  const int m_  = bid >> 8;                            // 0..7
  const int qg  = 8 * (7 - m_) + ((m_ & 1) ? v_ : (7 - v_));
  const int qmin = qg * 32;
  const size_t base = (size_t)bh * Lq * Dh;

  // Q fragments with scale*log2e folded in (B-operand: col=l31(q))
  const float QS = 0.125f * 1.4426950408889634f;
  u16x8 qc[4];
  {
    const float* qp = Q + base + (size_t)(qmin + l31) * Dh + h * 8;
    #pragma unroll
    for (int dc = 0; dc < 4; ++dc) {
      f32x4 lo = *(const f32x4*)(qp + dc * 16);
      f32x4 hi = *(const f32x4*)(qp + dc * 16 + 4);
      u16x8 f;
      #pragma unroll
      for (int j = 0; j < 4; ++j) {
        f[j]     = f2bf(lo[j] * QS);
        f[4 + j] = f2bf(hi[j] * QS);
      }
      qc[dc] = f;
    }
  }

  // wave's strip count: strips s = w, w+4, ... < S (S = qg+1 strips of 32 kv)
  const int Sw = qg + 1 - w;
  const int nw = (Sw > 0) ? ((Sw + 3) >> 2) : 0;

  const unsigned char* Wb = W + (size_t)(bh * 32) * TILEB;
  const int laneK = ((w & 1) * 32 + l31) * 16 + h * 1024;
  const int laneV = VOFF + ((w & 1) * 4 + h) * 1024 + l31 * 16;

  f32x16 accO0, accO1;
  #pragma unroll
  for (int i = 0; i < 16; ++i) { accO0[i] = 0.f; accO1[i] = 0.f; }
  float ls0 = 0.f, ls1 = 0.f;

  // plain per-strip loop: small register state, rely on 8 waves/SIMD TLP
  if (nw > 0) {
    const unsigned char* pT = Wb + (size_t)(w >> 1) * TILEB;
    int kv0 = w * 32;
    for (int j = 0; j < nw; ++j) {
      u16x8 kf[4], vf[4];
      {
        const unsigned char* p = pT + laneK;
        kf[0] = *(const u16x8*)(p);
        kf[1] = *(const u16x8*)(p + 2048);
        kf[2] = *(const u16x8*)(p + 4096);
        kf[3] = *(const u16x8*)(p + 6144);
      }
      {
        const unsigned char* p = pT + laneV;
        vf[0] = *(const u16x8*)(p);
        vf[1] = *(const u16x8*)(p + 512);
        vf[2] = *(const u16x8*)(p + 2048);
        vf[3] = *(const u16x8*)(p + 2560);
      }

      f32x16 s;
      #pragma unroll
      for (int i = 0; i < 16; ++i) s[i] = 0.f;
      __builtin_amdgcn_s_setprio(1);
      #pragma unroll
      for (int dc = 0; dc < 4; ++dc) s = mfma32(kf[dc], qc[dc], s);
      __builtin_amdgcn_s_setprio(0);

      // softmax numerator: P = exp2(s) (bias-free; 2^C0 cancels in normalize)
      float p[16];
      if (kv0 + 31 > qmin) {            // diagonal strip only
        const int qrow = qmin + l31;
        #pragma unroll
        for (int r = 0; r < 16; ++r) {
          float e = __builtin_amdgcn_exp2f(s[r]);
          const int kvg = kv0 + (r & 3) + 8 * (r >> 2) + 4 * h;
          p[r] = (kvg <= qrow) ? e : 0.0f;
        }
      } else {
        #pragma unroll
        for (int r = 0; r < 16; ++r)
          p[r] = __builtin_amdgcn_exp2f(s[r]);
      }
      ls0 += ((p[0] + p[1]) + (p[2] + p[3])) + ((p[4] + p[5]) + (p[6] + p[7]));
      ls1 += ((p[8] + p[9]) + (p[10] + p[11])) + ((p[12] + p[13]) + (p[14] + p[15]));

      unsigned pk[4][2];
      #pragma unroll
      for (int q4 = 0; q4 < 4; ++q4) {
        pk[q4][0] = cvtpk(p[q4 * 4 + 0], p[q4 * 4 + 1]);
        pk[q4][1] = cvtpk(p[q4 * 4 + 2], p[q4 * 4 + 3]);
      }
      __builtin_amdgcn_s_setprio(1);
      #pragma unroll
      for (int c2 = 0; c2 < 2; ++c2) {
        unsigned w0, w1, w2, w3;
        plswap(pk[2 * c2][0], pk[2 * c2 + 1][0], w0, w2);
        plswap(pk[2 * c2][1], pk[2 * c2 + 1][1], w1, w3);
        u32x4 pw = {w0, w1, w2, w3};
        u16x8 pf = __builtin_bit_cast(u16x8, pw);
        accO0 = mfma32(vf[c2 * 2 + 0], pf, accO0);
        accO1 = mfma32(vf[c2 * 2 + 1], pf, accO1);
      }
      __builtin_amdgcn_s_setprio(0);

      pT += 2 * TILEB;   // wave strides 4 strips = 2 tiles
      kv0 += 128;
    }
  }

  // sequential 3-round merge through one 8.4KB buffer
  float ls = ls0 + ls1;
  #pragma unroll
  for (int v = 1; v < 4; ++v) {
    __syncthreads();
    if (w == v) {
      float* m = &Mrg[lane][0];
      #pragma unroll
      for (int r = 0; r < 16; ++r) { m[r] = accO0[r]; m[16 + r] = accO1[r]; }
      m[32] = ls;
    }
    __syncthreads();
    if (w == 0) {
      const float* m = &Mrg[lane][0];
      #pragma unroll
      for (int r = 0; r < 16; ++r) { accO0[r] += m[r]; accO1[r] += m[16 + r]; }
      ls += m[32];
    }
  }
  if (w == 0) {
    ls += __shfl_xor(ls, 32);
    const float inv = 1.0f / ls;
    float* op = O + base + (size_t)(qmin + l31) * Dh;
    #pragma unroll
    for (int r = 0; r < 16; ++r) {
      const int d = (r & 3) + 8 * (r >> 2) + 4 * h;
      op[d]      = accO0[r] * inv;
      op[32 + d] = accO1[r] * inv;
    }
  }
}

extern "C" void kernel_launch(void* const* d_in, const int* in_sizes, int n_in,
                              void* d_out, int out_size, void* d_ws, size_t ws_size,
                              hipStream_t stream) {
  const float* Q = (const float*)d_in[0];
  const float* K = (const float*)d_in[1];
  const float* V = (const float*)d_in[2];
  // d_in[3]: causal mask — static structure, handled in-kernel.
  float* O = (float*)d_out;
  unsigned char* W = (unsigned char*)d_ws;   // 32*32*16384 = 16.8 MB

  repack<<<dim3(1024), dim3(256), 0, stream>>>(K, V, W);
  fattn_fwd<<<dim3(2048), dim3(256), 0, stream>>>(Q, W, O);
}

// Round 12
// 85.037 us; speedup vs baseline: 3.1207x; 3.1207x over previous
//
#include <hip/hip_runtime.h>

// Causal attention fwd: B=2,H=16,L=2048,D=64 fp32 in/out, bf16 MFMA inside.
//  1) repack: fp32 K,V -> bf16 FRAGMENT-MAJOR images in d_ws (K'[chunk][kv],
//     V'[chunk][d]); a wave's MFMA fragments are coalesced dwordx4 loads.
//     Also zeroes the job counter (graph-replay safe).
//  2) fattn_fwd: PERSISTENT work-stealing flash attention. 1280 blocks
//     (5/CU = the 96-reg residency ceiling) pop 2048 (bh,qg) jobs heavy-first
//     from an atomic counter -> CU load balance independent of dispatch order.
//     Per job: block = 32 q-rows; 4 waves split KV 4-ways (strip = 32 kv).
//     32x32x16 swapped-operand, in-register softmax (scale*log2e folded into
//     Q, bias-free exp2 — cancels in normalize), cvt_pk+permlane pack.
//     Register regime: launch_bounds(256,4), state ~96 regs, NO spill
//     (R8/R11 lesson: caps below state size => 100x scratch traffic).
// Workspace: 16MiB W images + 4B counter.

constexpr int Lq = 2048;
constexpr int Dh = 64;
constexpr int TILEB = 16384;  // K' 8KB + V' 8KB per 64-kv tile
constexpr int VOFF  = 8192;
constexpr size_t CNT_OFF = (size_t)32 * 32 * TILEB;   // 16 MiB
constexpr int NJOBS = 2048;   // 32 bh x 64 qg

typedef __attribute__((ext_vector_type(16))) float f32x16;
typedef __attribute__((ext_vector_type(4))) float f32x4;
typedef __attribute__((ext_vector_type(8))) unsigned short u16x8;
typedef __attribute__((ext_vector_type(4))) unsigned int u32x4;
typedef __attribute__((ext_vector_type(8))) __bf16 bf16x8;

__device__ __forceinline__ unsigned short f2bf(float f) {
  __bf16 h = (__bf16)f;
  return __builtin_bit_cast(unsigned short, h);
}
__device__ __forceinline__ unsigned cvtpk(float lo, float hi) {
  unsigned r;
  asm("v_cvt_pk_bf16_f32 %0, %1, %2" : "=v"(r) : "v"(lo), "v"(hi));
  return r;
}
__device__ __forceinline__ f32x16 mfma32(u16x8 a, u16x8 b, f32x16 c) {
  return __builtin_amdgcn_mfma_f32_32x32x16_bf16(
      __builtin_bit_cast(bf16x8, a), __builtin_bit_cast(bf16x8, b), c, 0, 0, 0);
}
__device__ __forceinline__ void plswap(unsigned a, unsigned b,
                                       unsigned& wlo, unsigned& whi) {
#if __has_builtin(__builtin_amdgcn_permlane32_swap)
  auto r = __builtin_amdgcn_permlane32_swap((int)a, (int)b, false, false);
  wlo = (unsigned)r[0];
  whi = (unsigned)r[1];
#else
  const int hh = (threadIdx.x >> 5) & 1;
  unsigned pa = (unsigned)__shfl_xor((int)a, 32);
  unsigned pb = (unsigned)__shfl_xor((int)b, 32);
  wlo = hh ? pb : a;
  whi = hh ? b : pa;
#endif
}

// ---------------- prepass: fp32 K,V -> bf16 fragment-major images ----------------
__global__ __launch_bounds__(256, 2)
void repack(const float* __restrict__ K, const float* __restrict__ V,
            unsigned char* __restrict__ W, int* cnt) {
  __shared__ unsigned short Vl[64][72];

  if (cnt && blockIdx.x == 0 && threadIdx.x == 0) *cnt = 0;

  const int tid = threadIdx.x;
  const int bt  = blockIdx.x;             // bh*32 + tile
  const int bh  = bt >> 5;
  const int tl  = bt & 31;
  const size_t src = (size_t)bh * Lq * Dh + (size_t)tl * 64 * Dh;
  unsigned char* img = W + (size_t)bt * TILEB;

  const int r  = tid >> 2;        // 0..63
  const int c2 = (tid & 3) * 2;   // chunk pair base

  {  // K': chunk c holds d in [8c,8c+8); K'[c][r] 16B at (c*64+r)*16
    const float* kp = K + src + (size_t)r * Dh + c2 * 8;
    f32x4 a = *(const f32x4*)kp;
    f32x4 b = *(const f32x4*)(kp + 4);
    f32x4 c = *(const f32x4*)(kp + 8);
    f32x4 d = *(const f32x4*)(kp + 12);
    u16x8 lo, hi;
    #pragma unroll
    for (int jj = 0; jj < 4; ++jj) {
      lo[jj] = f2bf(a[jj]); lo[4 + jj] = f2bf(b[jj]);
      hi[jj] = f2bf(c[jj]); hi[4 + jj] = f2bf(d[jj]);
    }
    *(u16x8*)(img + (c2 * 64 + r) * 16)       = lo;
    *(u16x8*)(img + ((c2 + 1) * 64 + r) * 16) = hi;
  }
  {  // V staged to LDS row-major [kv][d]
    const float* vp = V + src + (size_t)r * Dh + c2 * 8;
    f32x4 a = *(const f32x4*)vp;
    f32x4 b = *(const f32x4*)(vp + 4);
    f32x4 c = *(const f32x4*)(vp + 8);
    f32x4 d = *(const f32x4*)(vp + 12);
    u16x8 lo, hi;
    #pragma unroll
    for (int jj = 0; jj < 4; ++jj) {
      lo[jj] = f2bf(a[jj]); lo[4 + jj] = f2bf(b[jj]);
      hi[jj] = f2bf(c[jj]); hi[4 + jj] = f2bf(d[jj]);
    }
    *(u16x8*)&Vl[r][c2 * 8]     = lo;
    *(u16x8*)&Vl[r][c2 * 8 + 8] = hi;
  }
  __syncthreads();
  {  // V': chunk c holds kv in [8c,8c+8); V'[c][d] = V[8c+e][d]
    u16x8 lo, hi;
    #pragma unroll
    for (int e = 0; e < 8; ++e) {
      lo[e] = Vl[c2 * 8 + e][r];
      hi[e] = Vl[c2 * 8 + 8 + e][r];
    }
    *(u16x8*)(img + VOFF + (c2 * 64 + r) * 16)       = lo;
    *(u16x8*)(img + VOFF + ((c2 + 1) * 64 + r) * 16) = hi;
  }
}

// ---------------- main: persistent work-stealing flash attention ----------------
__global__ __launch_bounds__(256, 4)
void fattn_fwd(const float* __restrict__ Q, const unsigned char* __restrict__ W,
               float* __restrict__ O, int* cnt) {
  __shared__ float Mrg[64][33];   // one wave's partials per merge round
  __shared__ int jobLDS;

  const int tid  = threadIdx.x;
  const int lane = tid & 63;
  const int w    = tid >> 6;     // 0..3 = KV strip class (s == w mod 4)
  const int l31  = lane & 31;
  const int h    = lane >> 5;

  const float QS = 0.125f * 1.4426950408889634f;   // scale * log2e
  const int laneK = ((w & 1) * 32 + l31) * 16 + h * 1024;
  const int laneV = VOFF + ((w & 1) * 4 + h) * 1024 + l31 * 16;

  for (;;) {
    int j;
    if (cnt) {
      if (tid == 0) jobLDS = atomicAdd(cnt, 1);
      __syncthreads();
      j = jobLDS;               // read before the job's merge barriers (safe)
    } else {
      j = blockIdx.x;
    }
    if (j >= NJOBS) break;      // block-uniform exit

    // LPT job order: heavy q-groups first
    const int qg   = 63 - (j >> 5);
    const int bh   = j & 31;
    const int qmin = qg * 32;
    const size_t base = (size_t)bh * Lq * Dh;

    // Q fragments with scale*log2e folded in (B-operand: col=l31(q))
    u16x8 qc[4];
    {
      const float* qp = Q + base + (size_t)(qmin + l31) * Dh + h * 8;
      #pragma unroll
      for (int dc = 0; dc < 4; ++dc) {
        f32x4 lo = *(const f32x4*)(qp + dc * 16);
        f32x4 hi = *(const f32x4*)(qp + dc * 16 + 4);
        u16x8 f;
        #pragma unroll
        for (int jj = 0; jj < 4; ++jj) {
          f[jj]     = f2bf(lo[jj] * QS);
          f[4 + jj] = f2bf(hi[jj] * QS);
        }
        qc[dc] = f;
      }
    }

    // wave's strips: s = w, w+4, ... < qg+1
    const int Sw = qg + 1 - w;
    const int nw = (Sw > 0) ? ((Sw + 3) >> 2) : 0;

    f32x16 accO0, accO1;
    #pragma unroll
    for (int i = 0; i < 16; ++i) { accO0[i] = 0.f; accO1[i] = 0.f; }
    float ls0 = 0.f, ls1 = 0.f;

    if (nw > 0) {
      const unsigned char* pT =
          W + (size_t)(bh * 32 + (w >> 1)) * TILEB;
      int kv0 = w * 32;
      for (int jj = 0; jj < nw; ++jj) {
        u16x8 kf[4], vf[4];
        {
          const unsigned char* p = pT + laneK;
          kf[0] = *(const u16x8*)(p);
          kf[1] = *(const u16x8*)(p + 2048);
          kf[2] = *(const u16x8*)(p + 4096);
          kf[3] = *(const u16x8*)(p + 6144);
        }
        {
          const unsigned char* p = pT + laneV;
          vf[0] = *(const u16x8*)(p);
          vf[1] = *(const u16x8*)(p + 512);
          vf[2] = *(const u16x8*)(p + 2048);
          vf[3] = *(const u16x8*)(p + 2560);
        }

        f32x16 s;
        #pragma unroll
        for (int i = 0; i < 16; ++i) s[i] = 0.f;
        __builtin_amdgcn_s_setprio(1);
        #pragma unroll
        for (int dc = 0; dc < 4; ++dc) s = mfma32(kf[dc], qc[dc], s);
        __builtin_amdgcn_s_setprio(0);

        // P = exp2(s) (bias-free; global 2^C0 factor cancels in normalize)
        float p[16];
        if (kv0 + 31 > qmin) {            // diagonal strip only
          const int qrow = qmin + l31;
          #pragma unroll
          for (int r = 0; r < 16; ++r) {
            float e = __builtin_amdgcn_exp2f(s[r]);
            const int kvg = kv0 + (r & 3) + 8 * (r >> 2) + 4 * h;
            p[r] = (kvg <= qrow) ? e : 0.0f;
          }
        } else {
          #pragma unroll
          for (int r = 0; r < 16; ++r)
            p[r] = __builtin_amdgcn_exp2f(s[r]);
        }
        ls0 += ((p[0] + p[1]) + (p[2] + p[3])) + ((p[4] + p[5]) + (p[6] + p[7]));
        ls1 += ((p[8] + p[9]) + (p[10] + p[11])) + ((p[12] + p[13]) + (p[14] + p[15]));

        unsigned pk[4][2];
        #pragma unroll
        for (int q4 = 0; q4 < 4; ++q4) {
          pk[q4][0] = cvtpk(p[q4 * 4 + 0], p[q4 * 4 + 1]);
          pk[q4][1] = cvtpk(p[q4 * 4 + 2], p[q4 * 4 + 3]);
        }
        __builtin_amdgcn_s_setprio(1);
        #pragma unroll
        for (int c2 = 0; c2 < 2; ++c2) {
          unsigned w0, w1, w2, w3;
          plswap(pk[2 * c2][0], pk[2 * c2 + 1][0], w0, w2);
          plswap(pk[2 * c2][1], pk[2 * c2 + 1][1], w1, w3);
          u32x4 pw = {w0, w1, w2, w3};
          u16x8 pf = __builtin_bit_cast(u16x8, pw);
          accO0 = mfma32(vf[c2 * 2 + 0], pf, accO0);
          accO1 = mfma32(vf[c2 * 2 + 1], pf, accO1);
        }
        __builtin_amdgcn_s_setprio(0);

        pT += 2 * TILEB;   // wave strides 4 strips = 2 tiles
        kv0 += 128;
      }
    }

    // sequential 3-round merge through the 8.4KB buffer
    float ls = ls0 + ls1;
    #pragma unroll
    for (int v = 1; v < 4; ++v) {
      __syncthreads();
      if (w == v) {
        float* m = &Mrg[lane][0];
        #pragma unroll
        for (int r = 0; r < 16; ++r) { m[r] = accO0[r]; m[16 + r] = accO1[r]; }
        m[32] = ls;
      }
      __syncthreads();
      if (w == 0) {
        const float* m = &Mrg[lane][0];
        #pragma unroll
        for (int r = 0; r < 16; ++r) { accO0[r] += m[r]; accO1[r] += m[16 + r]; }
        ls += m[32];
      }
    }
    if (w == 0) {
      ls += __shfl_xor(ls, 32);
      const float inv = 1.0f / ls;
      float* op = O + base + (size_t)(qmin + l31) * Dh;
      #pragma unroll
      for (int r = 0; r < 16; ++r) {
        const int d = (r & 3) + 8 * (r >> 2) + 4 * h;
        op[d]      = accO0[r] * inv;
        op[32 + d] = accO1[r] * inv;
      }
    }

    if (!cnt) break;   // static fallback: one job per block
  }
}

extern "C" void kernel_launch(void* const* d_in, const int* in_sizes, int n_in,
                              void* d_out, int out_size, void* d_ws, size_t ws_size,
                              hipStream_t stream) {
  const float* Q = (const float*)d_in[0];
  const float* K = (const float*)d_in[1];
  const float* V = (const float*)d_in[2];
  // d_in[3]: causal mask — static structure, handled in-kernel.
  float* O = (float*)d_out;
  unsigned char* W = (unsigned char*)d_ws;

  int* cnt = (ws_size >= CNT_OFF + sizeof(int)) ? (int*)(W + CNT_OFF) : nullptr;

  repack<<<dim3(1024), dim3(256), 0, stream>>>(K, V, W, cnt);
  fattn_fwd<<<dim3(cnt ? 1280 : NJOBS), dim3(256), 0, stream>>>(Q, W, O, cnt);
}

// Round 13
// 49.810 us; speedup vs baseline: 5.3277x; 1.7072x over previous
//
#include <hip/hip_runtime.h>

// Causal attention fwd: B=2,H=16,L=2048,D=64 fp32 in/out, bf16 MFMA inside.
//  1) repack: fp32 K,V -> bf16 FRAGMENT-MAJOR images in d_ws (K'[chunk][kv],
//     V'[chunk][d]); a wave's MFMA fragments are coalesced dwordx4 loads.
//     Also zeroes the 8 per-XCD job counters (graph-replay safe).
//  2) fattn_fwd: persistent flash attention with XCD-LOCAL work stealing:
//     class c = bid&7 pops LPT-ordered jobs over bh in [4c,4c+4) only ->
//     2MB working set stays in that XCD's L2 (R12 lesson: global stealing
//     = 170MB HBM overfetch), stealing keeps CUs busy (R10 lesson: static
//     assignment drains at 32% occupancy). Grid 1280 = 5 blocks/CU = the
//     ~92-reg (VGPR+AGPR) residency ceiling.
//     Per job: block = 32 q-rows; 4 waves split KV 4-ways (strip = 32 kv).
//     32x32x16 swapped-operand, in-register softmax (scale*log2e folded
//     into Q, bias-free exp2 — cancels in normalize), cvt_pk+permlane.
// Workspace: 16MiB W images + 2KB counters.

constexpr int Lq = 2048;
constexpr int Dh = 64;
constexpr int TILEB = 16384;  // K' 8KB + V' 8KB per 64-kv tile
constexpr int VOFF  = 8192;
constexpr size_t CNT_OFF = (size_t)32 * 32 * TILEB;   // 16 MiB
constexpr int JOBS_PER_CLASS = 256;   // 4 bh x 64 qg

typedef __attribute__((ext_vector_type(16))) float f32x16;
typedef __attribute__((ext_vector_type(4))) float f32x4;
typedef __attribute__((ext_vector_type(8))) unsigned short u16x8;
typedef __attribute__((ext_vector_type(4))) unsigned int u32x4;
typedef __attribute__((ext_vector_type(8))) __bf16 bf16x8;

__device__ __forceinline__ unsigned short f2bf(float f) {
  __bf16 h = (__bf16)f;
  return __builtin_bit_cast(unsigned short, h);
}
__device__ __forceinline__ unsigned cvtpk(float lo, float hi) {
  unsigned r;
  asm("v_cvt_pk_bf16_f32 %0, %1, %2" : "=v"(r) : "v"(lo), "v"(hi));
  return r;
}
__device__ __forceinline__ f32x16 mfma32(u16x8 a, u16x8 b, f32x16 c) {
  return __builtin_amdgcn_mfma_f32_32x32x16_bf16(
      __builtin_bit_cast(bf16x8, a), __builtin_bit_cast(bf16x8, b), c, 0, 0, 0);
}
__device__ __forceinline__ void plswap(unsigned a, unsigned b,
                                       unsigned& wlo, unsigned& whi) {
#if __has_builtin(__builtin_amdgcn_permlane32_swap)
  auto r = __builtin_amdgcn_permlane32_swap((int)a, (int)b, false, false);
  wlo = (unsigned)r[0];
  whi = (unsigned)r[1];
#else
  const int hh = (threadIdx.x >> 5) & 1;
  unsigned pa = (unsigned)__shfl_xor((int)a, 32);
  unsigned pb = (unsigned)__shfl_xor((int)b, 32);
  wlo = hh ? pb : a;
  whi = hh ? b : pa;
#endif
}

// ---------------- prepass: fp32 K,V -> bf16 fragment-major images ----------------
__global__ __launch_bounds__(256, 2)
void repack(const float* __restrict__ K, const float* __restrict__ V,
            unsigned char* __restrict__ W, int* cnt) {
  __shared__ unsigned short Vl[64][72];

  if (cnt && blockIdx.x == 0 && threadIdx.x < 8) cnt[threadIdx.x * 64] = 0;

  const int tid = threadIdx.x;
  const int bt  = blockIdx.x;             // bh*32 + tile
  const int bh  = bt >> 5;
  const int tl  = bt & 31;
  const size_t src = (size_t)bh * Lq * Dh + (size_t)tl * 64 * Dh;
  unsigned char* img = W + (size_t)bt * TILEB;

  const int r  = tid >> 2;        // 0..63
  const int c2 = (tid & 3) * 2;   // chunk pair base

  {  // K': chunk c holds d in [8c,8c+8); K'[c][r] 16B at (c*64+r)*16
    const float* kp = K + src + (size_t)r * Dh + c2 * 8;
    f32x4 a = *(const f32x4*)kp;
    f32x4 b = *(const f32x4*)(kp + 4);
    f32x4 c = *(const f32x4*)(kp + 8);
    f32x4 d = *(const f32x4*)(kp + 12);
    u16x8 lo, hi;
    #pragma unroll
    for (int jj = 0; jj < 4; ++jj) {
      lo[jj] = f2bf(a[jj]); lo[4 + jj] = f2bf(b[jj]);
      hi[jj] = f2bf(c[jj]); hi[4 + jj] = f2bf(d[jj]);
    }
    *(u16x8*)(img + (c2 * 64 + r) * 16)       = lo;
    *(u16x8*)(img + ((c2 + 1) * 64 + r) * 16) = hi;
  }
  {  // V staged to LDS row-major [kv][d]
    const float* vp = V + src + (size_t)r * Dh + c2 * 8;
    f32x4 a = *(const f32x4*)vp;
    f32x4 b = *(const f32x4*)(vp + 4);
    f32x4 c = *(const f32x4*)(vp + 8);
    f32x4 d = *(const f32x4*)(vp + 12);
    u16x8 lo, hi;
    #pragma unroll
    for (int jj = 0; jj < 4; ++jj) {
      lo[jj] = f2bf(a[jj]); lo[4 + jj] = f2bf(b[jj]);
      hi[jj] = f2bf(c[jj]); hi[4 + jj] = f2bf(d[jj]);
    }
    *(u16x8*)&Vl[r][c2 * 8]     = lo;
    *(u16x8*)&Vl[r][c2 * 8 + 8] = hi;
  }
  __syncthreads();
  {  // V': chunk c holds kv in [8c,8c+8); V'[c][d] = V[8c+e][d]
    u16x8 lo, hi;
    #pragma unroll
    for (int e = 0; e < 8; ++e) {
      lo[e] = Vl[c2 * 8 + e][r];
      hi[e] = Vl[c2 * 8 + 8 + e][r];
    }
    *(u16x8*)(img + VOFF + (c2 * 64 + r) * 16)       = lo;
    *(u16x8*)(img + VOFF + ((c2 + 1) * 64 + r) * 16) = hi;
  }
}

// ---------------- main: XCD-local work-stealing flash attention ----------------
__global__ __launch_bounds__(256, 4)
void fattn_fwd(const float* __restrict__ Q, const unsigned char* __restrict__ W,
               float* __restrict__ O, int* cnt) {
  __shared__ float Mrg[64][33];   // one wave's partials per merge round
  __shared__ int jobLDS;

  const int tid  = threadIdx.x;
  const int lane = tid & 63;
  const int w    = tid >> 6;     // 0..3 = KV strip class (s == w mod 4)
  const int l31  = lane & 31;
  const int h    = lane >> 5;

  const int cls  = blockIdx.x & 7;          // XCD class: bh in [4*cls, 4*cls+4)
  int* qcnt = cnt ? (cnt + cls * 64) : nullptr;

  const float QS = 0.125f * 1.4426950408889634f;   // scale * log2e
  const int laneK = ((w & 1) * 32 + l31) * 16 + h * 1024;
  const int laneV = VOFF + ((w & 1) * 4 + h) * 1024 + l31 * 16;

  for (;;) {
    int j;
    if (qcnt) {
      if (tid == 0) jobLDS = atomicAdd(qcnt, 1);
      __syncthreads();
      j = jobLDS;
    } else {
      j = blockIdx.x >> 3;   // static fallback (grid must be 2048)
    }
    if (j >= JOBS_PER_CLASS) break;      // block-uniform exit

    // LPT within class: heavy q-groups first, 4 bh round-robin
    const int qg   = 63 - (j >> 2);
    const int bh   = cls * 4 + (j & 3);
    const int qmin = qg * 32;
    const size_t base = (size_t)bh * Lq * Dh;

    // Q fragments with scale*log2e folded in (B-operand: col=l31(q))
    u16x8 qc[4];
    {
      const float* qp = Q + base + (size_t)(qmin + l31) * Dh + h * 8;
      #pragma unroll
      for (int dc = 0; dc < 4; ++dc) {
        f32x4 lo = *(const f32x4*)(qp + dc * 16);
        f32x4 hi = *(const f32x4*)(qp + dc * 16 + 4);
        u16x8 f;
        #pragma unroll
        for (int jj = 0; jj < 4; ++jj) {
          f[jj]     = f2bf(lo[jj] * QS);
          f[4 + jj] = f2bf(hi[jj] * QS);
        }
        qc[dc] = f;
      }
    }

    // wave's strips: s = w, w+4, ... < qg+1
    const int Sw = qg + 1 - w;
    const int nw = (Sw > 0) ? ((Sw + 3) >> 2) : 0;

    f32x16 accO0, accO1;
    #pragma unroll
    for (int i = 0; i < 16; ++i) { accO0[i] = 0.f; accO1[i] = 0.f; }
    float ls0 = 0.f, ls1 = 0.f;

    if (nw > 0) {
      const unsigned char* pT =
          W + (size_t)(bh * 32 + (w >> 1)) * TILEB;
      int kv0 = w * 32;
      for (int jj = 0; jj < nw; ++jj) {
        u16x8 kf[4], vf[4];
        {
          const unsigned char* p = pT + laneK;
          kf[0] = *(const u16x8*)(p);
          kf[1] = *(const u16x8*)(p + 2048);
          kf[2] = *(const u16x8*)(p + 4096);
          kf[3] = *(const u16x8*)(p + 6144);
        }
        {
          const unsigned char* p = pT + laneV;
          vf[0] = *(const u16x8*)(p);
          vf[1] = *(const u16x8*)(p + 512);
          vf[2] = *(const u16x8*)(p + 2048);
          vf[3] = *(const u16x8*)(p + 2560);
        }

        f32x16 s;
        #pragma unroll
        for (int i = 0; i < 16; ++i) s[i] = 0.f;
        __builtin_amdgcn_s_setprio(1);
        #pragma unroll
        for (int dc = 0; dc < 4; ++dc) s = mfma32(kf[dc], qc[dc], s);
        __builtin_amdgcn_s_setprio(0);

        // P = exp2(s) (bias-free; global 2^C0 factor cancels in normalize)
        float p[16];
        if (kv0 + 31 > qmin) {            // diagonal strip only
          const int qrow = qmin + l31;
          #pragma unroll
          for (int r = 0; r < 16; ++r) {
            float e = __builtin_amdgcn_exp2f(s[r]);
            const int kvg = kv0 + (r & 3) + 8 * (r >> 2) + 4 * h;
            p[r] = (kvg <= qrow) ? e : 0.0f;
          }
        } else {
          #pragma unroll
          for (int r = 0; r < 16; ++r)
            p[r] = __builtin_amdgcn_exp2f(s[r]);
        }
        ls0 += ((p[0] + p[1]) + (p[2] + p[3])) + ((p[4] + p[5]) + (p[6] + p[7]));
        ls1 += ((p[8] + p[9]) + (p[10] + p[11])) + ((p[12] + p[13]) + (p[14] + p[15]));

        unsigned pk[4][2];
        #pragma unroll
        for (int q4 = 0; q4 < 4; ++q4) {
          pk[q4][0] = cvtpk(p[q4 * 4 + 0], p[q4 * 4 + 1]);
          pk[q4][1] = cvtpk(p[q4 * 4 + 2], p[q4 * 4 + 3]);
        }
        __builtin_amdgcn_s_setprio(1);
        #pragma unroll
        for (int c2 = 0; c2 < 2; ++c2) {
          unsigned w0, w1, w2, w3;
          plswap(pk[2 * c2][0], pk[2 * c2 + 1][0], w0, w2);
          plswap(pk[2 * c2][1], pk[2 * c2 + 1][1], w1, w3);
          u32x4 pw = {w0, w1, w2, w3};
          u16x8 pf = __builtin_bit_cast(u16x8, pw);
          accO0 = mfma32(vf[c2 * 2 + 0], pf, accO0);
          accO1 = mfma32(vf[c2 * 2 + 1], pf, accO1);
        }
        __builtin_amdgcn_s_setprio(0);

        pT += 2 * TILEB;   // wave strides 4 strips = 2 tiles
        kv0 += 128;
      }
    }

    // sequential 3-round merge through the 8.4KB buffer
    float ls = ls0 + ls1;
    #pragma unroll
    for (int v = 1; v < 4; ++v) {
      __syncthreads();
      if (w == v) {
        float* m = &Mrg[lane][0];
        #pragma unroll
        for (int r = 0; r < 16; ++r) { m[r] = accO0[r]; m[16 + r] = accO1[r]; }
        m[32] = ls;
      }
      __syncthreads();
      if (w == 0) {
        const float* m = &Mrg[lane][0];
        #pragma unroll
        for (int r = 0; r < 16; ++r) { accO0[r] += m[r]; accO1[r] += m[16 + r]; }
        ls += m[32];
      }
    }
    if (w == 0) {
      ls += __shfl_xor(ls, 32);
      const float inv = 1.0f / ls;
      float* op = O + base + (size_t)(qmin + l31) * Dh;
      #pragma unroll
      for (int r = 0; r < 16; ++r) {
        const int d = (r & 3) + 8 * (r >> 2) + 4 * h;
        op[d]      = accO0[r] * inv;
        op[32 + d] = accO1[r] * inv;
      }
    }

    if (!qcnt) break;   // static fallback: one job per block
  }
}

extern "C" void kernel_launch(void* const* d_in, const int* in_sizes, int n_in,
                              void* d_out, int out_size, void* d_ws, size_t ws_size,
                              hipStream_t stream) {
  const float* Q = (const float*)d_in[0];
  const float* K = (const float*)d_in[1];
  const float* V = (const float*)d_in[2];
  // d_in[3]: causal mask — static structure, handled in-kernel.
  float* O = (float*)d_out;
  unsigned char* W = (unsigned char*)d_ws;

  int* cnt = (ws_size >= CNT_OFF + 2048) ? (int*)(W + CNT_OFF) : nullptr;

  repack<<<dim3(1024), dim3(256), 0, stream>>>(K, V, W, cnt);
  fattn_fwd<<<dim3(cnt ? 1280 : 2048), dim3(256), 0, stream>>>(Q, W, O, cnt);
}

// Round 17
// 48.957 us; speedup vs baseline: 5.4205x; 1.0174x over previous
//
#include <hip/hip_runtime.h>

// Causal attention fwd: B=2,H=16,L=2048,D=64 fp32 in/out, bf16 MFMA inside.
//  1) repack: fp32 K,V -> bf16 FRAGMENT-MAJOR images in d_ws (K'[chunk][kv],
//     V'[chunk][d]); a wave's MFMA fragments are coalesced dwordx4 loads.
//     Zeroes the 8 per-XCD job counters (graph-replay safe).
//  2) fattn_fwd: persistent XCD-local work-stealing flash attention (R13
//     verified base) + R17: DUAL INDEPENDENT STRIP CHAINS per iteration —
//     all 16 dwordx4 loads for strips A,B issued up front, compute A covers
//     B's latency. Pure HIP (R14-R16 lesson: reg-dest asm loads + deferred
//     waitcnt are unsound — allocator copies in-flight values).
//     launch_bounds(256,2): both chains live, no spill (R8/R11 lesson).
// Workspace: 16MiB W images + 2KB counters.

constexpr int Lq = 2048;
constexpr int Dh = 64;
constexpr int TILEB = 16384;  // K' 8KB + V' 8KB per 64-kv tile
constexpr int VOFF  = 8192;
constexpr size_t CNT_OFF = (size_t)32 * 32 * TILEB;   // 16 MiB
constexpr int JOBS_PER_CLASS = 256;   // 4 bh x 64 qg
constexpr size_t SSTRIDE = 2 * (size_t)TILEB;  // per local strip (128 kv)

typedef __attribute__((ext_vector_type(16))) float f32x16;
typedef __attribute__((ext_vector_type(4))) float f32x4;
typedef __attribute__((ext_vector_type(8))) unsigned short u16x8;
typedef __attribute__((ext_vector_type(4))) unsigned int u32x4;
typedef __attribute__((ext_vector_type(8))) __bf16 bf16x8;

__device__ __forceinline__ unsigned short f2bf(float f) {
  __bf16 h = (__bf16)f;
  return __builtin_bit_cast(unsigned short, h);
}
__device__ __forceinline__ unsigned cvtpk(float lo, float hi) {
  unsigned r;
  asm("v_cvt_pk_bf16_f32 %0, %1, %2" : "=v"(r) : "v"(lo), "v"(hi));
  return r;
}
__device__ __forceinline__ f32x16 mfma32(u16x8 a, u16x8 b, f32x16 c) {
  return __builtin_amdgcn_mfma_f32_32x32x16_bf16(
      __builtin_bit_cast(bf16x8, a), __builtin_bit_cast(bf16x8, b), c, 0, 0, 0);
}
__device__ __forceinline__ void plswap(unsigned a, unsigned b,
                                       unsigned& wlo, unsigned& whi) {
#if __has_builtin(__builtin_amdgcn_permlane32_swap)
  auto r = __builtin_amdgcn_permlane32_swap((int)a, (int)b, false, false);
  wlo = (unsigned)r[0];
  whi = (unsigned)r[1];
#else
  const int hh = (threadIdx.x >> 5) & 1;
  unsigned pa = (unsigned)__shfl_xor((int)a, 32);
  unsigned pb = (unsigned)__shfl_xor((int)b, 32);
  wlo = hh ? pb : a;
  whi = hh ? b : pa;
#endif
}

// ---------------- prepass: fp32 K,V -> bf16 fragment-major images ----------------
__global__ __launch_bounds__(256, 2)
void repack(const float* __restrict__ K, const float* __restrict__ V,
            unsigned char* __restrict__ W, int* cnt) {
  __shared__ unsigned short Vl[64][72];

  if (cnt && blockIdx.x == 0 && threadIdx.x < 8) cnt[threadIdx.x * 64] = 0;

  const int tid = threadIdx.x;
  const int bt  = blockIdx.x;             // bh*32 + tile
  const int bh  = bt >> 5;
  const int tl  = bt & 31;
  const size_t src = (size_t)bh * Lq * Dh + (size_t)tl * 64 * Dh;
  unsigned char* img = W + (size_t)bt * TILEB;

  const int r  = tid >> 2;        // 0..63
  const int c2 = (tid & 3) * 2;   // chunk pair base

  {  // K': chunk c holds d in [8c,8c+8); K'[c][r] 16B at (c*64+r)*16
    const float* kp = K + src + (size_t)r * Dh + c2 * 8;
    f32x4 a = *(const f32x4*)kp;
    f32x4 b = *(const f32x4*)(kp + 4);
    f32x4 c = *(const f32x4*)(kp + 8);
    f32x4 d = *(const f32x4*)(kp + 12);
    u16x8 lo, hi;
    #pragma unroll
    for (int jj = 0; jj < 4; ++jj) {
      lo[jj] = f2bf(a[jj]); lo[4 + jj] = f2bf(b[jj]);
      hi[jj] = f2bf(c[jj]); hi[4 + jj] = f2bf(d[jj]);
    }
    *(u16x8*)(img + (c2 * 64 + r) * 16)       = lo;
    *(u16x8*)(img + ((c2 + 1) * 64 + r) * 16) = hi;
  }
  {  // V staged to LDS row-major [kv][d]
    const float* vp = V + src + (size_t)r * Dh + c2 * 8;
    f32x4 a = *(const f32x4*)vp;
    f32x4 b = *(const f32x4*)(vp + 4);
    f32x4 c = *(const f32x4*)(vp + 8);
    f32x4 d = *(const f32x4*)(vp + 12);
    u16x8 lo, hi;
    #pragma unroll
    for (int jj = 0; jj < 4; ++jj) {
      lo[jj] = f2bf(a[jj]); lo[4 + jj] = f2bf(b[jj]);
      hi[jj] = f2bf(c[jj]); hi[4 + jj] = f2bf(d[jj]);
    }
    *(u16x8*)&Vl[r][c2 * 8]     = lo;
    *(u16x8*)&Vl[r][c2 * 8 + 8] = hi;
  }
  __syncthreads();
  {  // V': chunk c holds kv in [8c,8c+8); V'[c][d] = V[8c+e][d]
    u16x8 lo, hi;
    #pragma unroll
    for (int e = 0; e < 8; ++e) {
      lo[e] = Vl[c2 * 8 + e][r];
      hi[e] = Vl[c2 * 8 + 8 + e][r];
    }
    *(u16x8*)(img + VOFF + (c2 * 64 + r) * 16)       = lo;
    *(u16x8*)(img + VOFF + ((c2 + 1) * 64 + r) * 16) = hi;
  }
}

// ---------------- main: dual-chain XCD-local work-stealing flash attention ----------------
__global__ __launch_bounds__(256, 2)
void fattn_fwd(const float* __restrict__ Q, const unsigned char* __restrict__ W,
               float* __restrict__ O, int* cnt) {
  __shared__ float Mrg[64][33];   // one wave's partials per merge round
  __shared__ int jobLDS;

  const int tid  = threadIdx.x;
  const int lane = tid & 63;
  const int w    = tid >> 6;     // 0..3 = KV strip class (s == w mod 4)
  const int l31  = lane & 31;
  const int h    = lane >> 5;

  const int cls  = blockIdx.x & 7;          // XCD class: bh in [4*cls, 4*cls+4)
  int* qcnt = cnt ? (cnt + cls * 64) : nullptr;

  const float QS = 0.125f * 1.4426950408889634f;   // scale * log2e
  const int laneK = ((w & 1) * 32 + l31) * 16 + h * 1024;
  const int laneV = VOFF + ((w & 1) * 4 + h) * 1024 + l31 * 16;

  for (;;) {
    int j;
    if (qcnt) {
      if (tid == 0) jobLDS = atomicAdd(qcnt, 1);
      __syncthreads();
      j = jobLDS;
    } else {
      j = blockIdx.x >> 3;   // static fallback (grid must be 2048)
    }
    if (j >= JOBS_PER_CLASS) break;

    // LPT within class: heavy q-groups first, 4 bh round-robin
    const int qg   = 63 - (j >> 2);
    const int bh   = cls * 4 + (j & 3);
    const int qmin = qg * 32;
    const size_t base = (size_t)bh * Lq * Dh;

    // Q fragments with scale*log2e folded in (B-operand: col=l31(q))
    u16x8 qc[4];
    {
      const float* qp = Q + base + (size_t)(qmin + l31) * Dh + h * 8;
      #pragma unroll
      for (int dc = 0; dc < 4; ++dc) {
        f32x4 lo = *(const f32x4*)(qp + dc * 16);
        f32x4 hi = *(const f32x4*)(qp + dc * 16 + 4);
        u16x8 f;
        #pragma unroll
        for (int jj = 0; jj < 4; ++jj) {
          f[jj]     = f2bf(lo[jj] * QS);
          f[4 + jj] = f2bf(hi[jj] * QS);
        }
        qc[dc] = f;
      }
    }

    // wave's strips: s = w, w+4, ... < qg+1
    const int Sw = qg + 1 - w;
    const int nw = (Sw > 0) ? ((Sw + 3) >> 2) : 0;

    f32x16 accO0, accO1;
    #pragma unroll
    for (int i = 0; i < 16; ++i) { accO0[i] = 0.f; accO1[i] = 0.f; }
    float ls0 = 0.f, ls1 = 0.f;

    if (nw > 0) {
      const unsigned char* pT = W + (size_t)(bh * 32 + (w >> 1)) * TILEB;

      auto ldK = [&](u16x8 (&kf)[4], const unsigned char* b_) {
        const unsigned char* p = b_ + laneK;
        kf[0] = *(const u16x8*)(p);
        kf[1] = *(const u16x8*)(p + 2048);
        kf[2] = *(const u16x8*)(p + 4096);
        kf[3] = *(const u16x8*)(p + 6144);
      };
      auto ldV = [&](u16x8 (&vf)[4], const unsigned char* b_) {
        const unsigned char* p = b_ + laneV;
        vf[0] = *(const u16x8*)(p);
        vf[1] = *(const u16x8*)(p + 512);
        vf[2] = *(const u16x8*)(p + 2048);
        vf[3] = *(const u16x8*)(p + 2560);
      };

      // one strip: QK -> exp/mask -> lsum -> pack -> PV (R13-verified math)
      auto strip = [&](const u16x8 (&kf)[4], const u16x8 (&vf)[4], int kv0) {
        f32x16 s;
        #pragma unroll
        for (int i = 0; i < 16; ++i) s[i] = 0.f;
        __builtin_amdgcn_s_setprio(1);
        #pragma unroll
        for (int dc = 0; dc < 4; ++dc) s = mfma32(kf[dc], qc[dc], s);
        __builtin_amdgcn_s_setprio(0);

        // P = exp2(s) (bias-free; global 2^C0 factor cancels in normalize)
        float p[16];
        if (kv0 + 31 > qmin) {            // diagonal strip only
          const int qrow = qmin + l31;
          #pragma unroll
          for (int r = 0; r < 16; ++r) {
            float e = __builtin_amdgcn_exp2f(s[r]);
            const int kvg = kv0 + (r & 3) + 8 * (r >> 2) + 4 * h;
            p[r] = (kvg <= qrow) ? e : 0.0f;
          }
        } else {
          #pragma unroll
          for (int r = 0; r < 16; ++r)
            p[r] = __builtin_amdgcn_exp2f(s[r]);
        }
        ls0 += ((p[0] + p[1]) + (p[2] + p[3])) + ((p[4] + p[5]) + (p[6] + p[7]));
        ls1 += ((p[8] + p[9]) + (p[10] + p[11])) + ((p[12] + p[13]) + (p[14] + p[15]));

        unsigned pk[4][2];
        #pragma unroll
        for (int q4 = 0; q4 < 4; ++q4) {
          pk[q4][0] = cvtpk(p[q4 * 4 + 0], p[q4 * 4 + 1]);
          pk[q4][1] = cvtpk(p[q4 * 4 + 2], p[q4 * 4 + 3]);
        }
        __builtin_amdgcn_s_setprio(1);
        #pragma unroll
        for (int c2 = 0; c2 < 2; ++c2) {
          unsigned w0, w1, w2, w3;
          plswap(pk[2 * c2][0], pk[2 * c2 + 1][0], w0, w2);
          plswap(pk[2 * c2][1], pk[2 * c2 + 1][1], w1, w3);
          u32x4 pw = {w0, w1, w2, w3};
          u16x8 pf = __builtin_bit_cast(u16x8, pw);
          accO0 = mfma32(vf[c2 * 2 + 0], pf, accO0);
          accO1 = mfma32(vf[c2 * 2 + 1], pf, accO1);
        }
        __builtin_amdgcn_s_setprio(0);
      };

      int jj = 0;
      int kv0 = w * 32;
      // dual-chain: A,B loads all issued before A's compute; A's compute
      // (~350cy MFMA+VALU) covers B's load latency. Chains independent
      // except accumulator chaining (normal MFMA pattern).
      for (; jj + 2 <= nw; jj += 2) {
        u16x8 kfA[4], vfA[4], kfB[4], vfB[4];
        ldK(kfA, pT);
        ldV(vfA, pT);
        ldK(kfB, pT + SSTRIDE);
        ldV(vfB, pT + SSTRIDE);
        strip(kfA, vfA, kv0);
        strip(kfB, vfB, kv0 + 128);
        pT += 2 * SSTRIDE;
        kv0 += 256;
      }
      if (jj < nw) {
        u16x8 kfA[4], vfA[4];
        ldK(kfA, pT);
        ldV(vfA, pT);
        strip(kfA, vfA, kv0);
      }
    }

    // sequential 3-round merge through the 8.4KB buffer
    float ls = ls0 + ls1;
    #pragma unroll
    for (int v = 1; v < 4; ++v) {
      __syncthreads();
      if (w == v) {
        float* m = &Mrg[lane][0];
        #pragma unroll
        for (int r = 0; r < 16; ++r) { m[r] = accO0[r]; m[16 + r] = accO1[r]; }
        m[32] = ls;
      }
      __syncthreads();
      if (w == 0) {
        const float* m = &Mrg[lane][0];
        #pragma unroll
        for (int r = 0; r < 16; ++r) { accO0[r] += m[r]; accO1[r] += m[16 + r]; }
        ls += m[32];
      }
    }
    if (w == 0) {
      ls += __shfl_xor(ls, 32);
      const float inv = 1.0f / ls;
      float* op = O + base + (size_t)(qmin + l31) * Dh;
      #pragma unroll
      for (int r = 0; r < 16; ++r) {
        const int d = (r & 3) + 8 * (r >> 2) + 4 * h;
        op[d]      = accO0[r] * inv;
        op[32 + d] = accO1[r] * inv;
      }
    }

    if (!qcnt) break;   // static fallback: one job per block
  }
}

extern "C" void kernel_launch(void* const* d_in, const int* in_sizes, int n_in,
                              void* d_out, int out_size, void* d_ws, size_t ws_size,
                              hipStream_t stream) {
  const float* Q = (const float*)d_in[0];
  const float* K = (const float*)d_in[1];
  const float* V = (const float*)d_in[2];
  // d_in[3]: causal mask — static structure, handled in-kernel.
  float* O = (float*)d_out;
  unsigned char* W = (unsigned char*)d_ws;

  int* cnt = (ws_size >= CNT_OFF + 2048) ? (int*)(W + CNT_OFF) : nullptr;

  repack<<<dim3(1024), dim3(256), 0, stream>>>(K, V, W, cnt);
  fattn_fwd<<<dim3(cnt ? 1280 : 2048), dim3(256), 0, stream>>>(Q, W, O, cnt);
}

// Round 18
// 47.491 us; speedup vs baseline: 5.5879x; 1.0309x over previous
//
#include <hip/hip_runtime.h>

// Causal attention fwd: B=2,H=16,L=2048,D=64 fp32 in/out, bf16 MFMA inside.
//  1) repack: fp32 K,V -> bf16 FRAGMENT-MAJOR images in d_ws (K'[chunk][kv],
//     V'[chunk][d]); MFMA fragments = coalesced dwordx4 loads. Zeroes the
//     8 per-XCD job counters.
//  2) fattn_fwd: persistent XCD-local work-stealing flash attention.
//     R18: DUAL Q-GROUPS PER WAVE — job = (bh, qpair) of 64 q rows; each
//     wave shares its K/V fragments across both 32-row q-groups: 8 loads
//     feed 16 MFMAs + 2 softmaxes (2x work per load-stall, QK_B overlaps
//     softmax_A on the MFMA pipe). Interior strips are branchless (no mask,
//     no kv0); the two diagonal strips are peeled (owner parity == w&1).
// Workspace: 16MiB W images + 2KB counters.

constexpr int Lq = 2048;
constexpr int Dh = 64;
constexpr int TILEB = 16384;  // K' 8KB + V' 8KB per 64-kv tile
constexpr int VOFF  = 8192;
constexpr size_t CNT_OFF = (size_t)32 * 32 * TILEB;   // 16 MiB
constexpr int JOBS_PER_CLASS = 128;   // 4 bh x 32 qpairs

typedef __attribute__((ext_vector_type(16))) float f32x16;
typedef __attribute__((ext_vector_type(4))) float f32x4;
typedef __attribute__((ext_vector_type(8))) unsigned short u16x8;
typedef __attribute__((ext_vector_type(4))) unsigned int u32x4;
typedef __attribute__((ext_vector_type(8))) __bf16 bf16x8;

__device__ __forceinline__ unsigned short f2bf(float f) {
  __bf16 h = (__bf16)f;
  return __builtin_bit_cast(unsigned short, h);
}
__device__ __forceinline__ unsigned cvtpk(float lo, float hi) {
  unsigned r;
  asm("v_cvt_pk_bf16_f32 %0, %1, %2" : "=v"(r) : "v"(lo), "v"(hi));
  return r;
}
__device__ __forceinline__ f32x16 mfma32(u16x8 a, u16x8 b, f32x16 c) {
  return __builtin_amdgcn_mfma_f32_32x32x16_bf16(
      __builtin_bit_cast(bf16x8, a), __builtin_bit_cast(bf16x8, b), c, 0, 0, 0);
}
__device__ __forceinline__ void plswap(unsigned a, unsigned b,
                                       unsigned& wlo, unsigned& whi) {
#if __has_builtin(__builtin_amdgcn_permlane32_swap)
  auto r = __builtin_amdgcn_permlane32_swap((int)a, (int)b, false, false);
  wlo = (unsigned)r[0];
  whi = (unsigned)r[1];
#else
  const int hh = (threadIdx.x >> 5) & 1;
  unsigned pa = (unsigned)__shfl_xor((int)a, 32);
  unsigned pb = (unsigned)__shfl_xor((int)b, 32);
  wlo = hh ? pb : a;
  whi = hh ? b : pa;
#endif
}

// ---------------- prepass: fp32 K,V -> bf16 fragment-major images ----------------
__global__ __launch_bounds__(256, 2)
void repack(const float* __restrict__ K, const float* __restrict__ V,
            unsigned char* __restrict__ W, int* cnt) {
  __shared__ unsigned short Vl[64][72];

  if (cnt && blockIdx.x == 0 && threadIdx.x < 8) cnt[threadIdx.x * 64] = 0;

  const int tid = threadIdx.x;
  const int bt  = blockIdx.x;             // bh*32 + tile
  const int bh  = bt >> 5;
  const int tl  = bt & 31;
  const size_t src = (size_t)bh * Lq * Dh + (size_t)tl * 64 * Dh;
  unsigned char* img = W + (size_t)bt * TILEB;

  const int r  = tid >> 2;        // 0..63
  const int c2 = (tid & 3) * 2;   // chunk pair base

  {  // K': chunk c holds d in [8c,8c+8); K'[c][r] 16B at (c*64+r)*16
    const float* kp = K + src + (size_t)r * Dh + c2 * 8;
    f32x4 a = *(const f32x4*)kp;
    f32x4 b = *(const f32x4*)(kp + 4);
    f32x4 c = *(const f32x4*)(kp + 8);
    f32x4 d = *(const f32x4*)(kp + 12);
    u16x8 lo, hi;
    #pragma unroll
    for (int jj = 0; jj < 4; ++jj) {
      lo[jj] = f2bf(a[jj]); lo[4 + jj] = f2bf(b[jj]);
      hi[jj] = f2bf(c[jj]); hi[4 + jj] = f2bf(d[jj]);
    }
    *(u16x8*)(img + (c2 * 64 + r) * 16)       = lo;
    *(u16x8*)(img + ((c2 + 1) * 64 + r) * 16) = hi;
  }
  {  // V staged to LDS row-major [kv][d]
    const float* vp = V + src + (size_t)r * Dh + c2 * 8;
    f32x4 a = *(const f32x4*)vp;
    f32x4 b = *(const f32x4*)(vp + 4);
    f32x4 c = *(const f32x4*)(vp + 8);
    f32x4 d = *(const f32x4*)(vp + 12);
    u16x8 lo, hi;
    #pragma unroll
    for (int jj = 0; jj < 4; ++jj) {
      lo[jj] = f2bf(a[jj]); lo[4 + jj] = f2bf(b[jj]);
      hi[jj] = f2bf(c[jj]); hi[4 + jj] = f2bf(d[jj]);
    }
    *(u16x8*)&Vl[r][c2 * 8]     = lo;
    *(u16x8*)&Vl[r][c2 * 8 + 8] = hi;
  }
  __syncthreads();
  {  // V': chunk c holds kv in [8c,8c+8); V'[c][d] = V[8c+e][d]
    u16x8 lo, hi;
    #pragma unroll
    for (int e = 0; e < 8; ++e) {
      lo[e] = Vl[c2 * 8 + e][r];
      hi[e] = Vl[c2 * 8 + 8 + e][r];
    }
    *(u16x8*)(img + VOFF + (c2 * 64 + r) * 16)       = lo;
    *(u16x8*)(img + VOFF + ((c2 + 1) * 64 + r) * 16) = hi;
  }
}

// ---------------- main: dual-q-group XCD-local work-stealing flash attention ----------------
__global__ __launch_bounds__(256, 2)
void fattn_fwd(const float* __restrict__ Q, const unsigned char* __restrict__ W,
               float* __restrict__ O, int* cnt) {
  __shared__ float Mrg[64][66];   // one wave's dual partials per merge round
  __shared__ int jobLDS;

  const int tid  = threadIdx.x;
  const int lane = tid & 63;
  const int w    = tid >> 6;     // 0..3 = KV strip class (s == w mod 4)
  const int l31  = lane & 31;
  const int h    = lane >> 5;

  const int cls  = blockIdx.x & 7;          // XCD class: bh in [4*cls, 4*cls+4)
  int* qcnt = cnt ? (cnt + cls * 64) : nullptr;

  const float QS = 0.125f * 1.4426950408889634f;   // scale * log2e
  const int laneK = ((w & 1) * 32 + l31) * 16 + h * 1024;
  const int laneV = VOFF + ((w & 1) * 4 + h) * 1024 + l31 * 16;

  for (;;) {
    int j;
    if (qcnt) {
      if (tid == 0) jobLDS = atomicAdd(qcnt, 1);
      __syncthreads();
      j = jobLDS;
    } else {
      j = blockIdx.x >> 3;   // static fallback (grid must be 1024)
    }
    if (j >= JOBS_PER_CLASS) break;

    // LPT within class: heavy q-pairs first, 4 bh round-robin
    const int qp   = 31 - (j >> 2);
    const int bh   = cls * 4 + (j & 3);
    const int qmA  = qp * 64;          // group A rows [qmA, qmA+32)
    const int qmB  = qmA + 32;         // group B rows [qmB, qmB+32)
    const size_t base = (size_t)bh * Lq * Dh;

    // Q fragments for BOTH groups (B-operand: col=l31(q)), scale folded in
    u16x8 qcA[4], qcB[4];
    #pragma unroll
    for (int g = 0; g < 2; ++g) {
      const float* qp_ = Q + base + (size_t)((g ? qmB : qmA) + l31) * Dh + h * 8;
      #pragma unroll
      for (int dc = 0; dc < 4; ++dc) {
        f32x4 lo = *(const f32x4*)(qp_ + dc * 16);
        f32x4 hi = *(const f32x4*)(qp_ + dc * 16 + 4);
        u16x8 f;
        #pragma unroll
        for (int jj = 0; jj < 4; ++jj) {
          f[jj]     = f2bf(lo[jj] * QS);
          f[4 + jj] = f2bf(hi[jj] * QS);
        }
        (g ? qcB : qcA)[dc] = f;
      }
    }

    f32x16 aA0, aA1, aB0, aB1;
    #pragma unroll
    for (int i = 0; i < 16; ++i) { aA0[i] = 0.f; aA1[i] = 0.f; aB0[i] = 0.f; aB1[i] = 0.f; }
    float lsA0 = 0.f, lsA1 = 0.f, lsB0 = 0.f, lsB1 = 0.f;

    // one strip vs both q-groups. Bools are call-site constants -> folded.
    auto strip = [&](const unsigned char* pTile, int kv0,
                     bool doA, bool maskA, bool maskB) {
      u16x8 kf[4], vf[4];
      {
        const unsigned char* p = pTile + laneK;
        kf[0] = *(const u16x8*)(p);
        kf[1] = *(const u16x8*)(p + 2048);
        kf[2] = *(const u16x8*)(p + 4096);
        kf[3] = *(const u16x8*)(p + 6144);
      }
      {
        const unsigned char* p = pTile + laneV;
        vf[0] = *(const u16x8*)(p);
        vf[1] = *(const u16x8*)(p + 512);
        vf[2] = *(const u16x8*)(p + 2048);
        vf[3] = *(const u16x8*)(p + 2560);
      }

      f32x16 sA, sB;
      #pragma unroll
      for (int i = 0; i < 16; ++i) { sA[i] = 0.f; sB[i] = 0.f; }
      __builtin_amdgcn_s_setprio(1);
      if (doA) {
        #pragma unroll
        for (int dc = 0; dc < 4; ++dc) sA = mfma32(kf[dc], qcA[dc], sA);
      }
      #pragma unroll
      for (int dc = 0; dc < 4; ++dc) sB = mfma32(kf[dc], qcB[dc], sB);
      __builtin_amdgcn_s_setprio(0);

      // ---- group A: softmax + PV ----
      if (doA) {
        float p[16];
        if (maskA) {
          const int qrow = qmA + l31;
          #pragma unroll
          for (int r = 0; r < 16; ++r) {
            float e = __builtin_amdgcn_exp2f(sA[r]);
            const int kvg = kv0 + (r & 3) + 8 * (r >> 2) + 4 * h;
            p[r] = (kvg <= qrow) ? e : 0.0f;
          }
        } else {
          #pragma unroll
          for (int r = 0; r < 16; ++r) p[r] = __builtin_amdgcn_exp2f(sA[r]);
        }
        lsA0 += ((p[0] + p[1]) + (p[2] + p[3])) + ((p[4] + p[5]) + (p[6] + p[7]));
        lsA1 += ((p[8] + p[9]) + (p[10] + p[11])) + ((p[12] + p[13]) + (p[14] + p[15]));
        unsigned pk[4][2];
        #pragma unroll
        for (int q4 = 0; q4 < 4; ++q4) {
          pk[q4][0] = cvtpk(p[q4 * 4 + 0], p[q4 * 4 + 1]);
          pk[q4][1] = cvtpk(p[q4 * 4 + 2], p[q4 * 4 + 3]);
        }
        __builtin_amdgcn_s_setprio(1);
        #pragma unroll
        for (int c2 = 0; c2 < 2; ++c2) {
          unsigned w0, w1, w2, w3;
          plswap(pk[2 * c2][0], pk[2 * c2 + 1][0], w0, w2);
          plswap(pk[2 * c2][1], pk[2 * c2 + 1][1], w1, w3);
          u32x4 pw = {w0, w1, w2, w3};
          u16x8 pf = __builtin_bit_cast(u16x8, pw);
          aA0 = mfma32(vf[c2 * 2 + 0], pf, aA0);
          aA1 = mfma32(vf[c2 * 2 + 1], pf, aA1);
        }
        __builtin_amdgcn_s_setprio(0);
      }

      // ---- group B: softmax + PV ----
      {
        float p[16];
        if (maskB) {
          const int qrow = qmB + l31;
          #pragma unroll
          for (int r = 0; r < 16; ++r) {
            float e = __builtin_amdgcn_exp2f(sB[r]);
            const int kvg = kv0 + (r & 3) + 8 * (r >> 2) + 4 * h;
            p[r] = (kvg <= qrow) ? e : 0.0f;
          }
        } else {
          #pragma unroll
          for (int r = 0; r < 16; ++r) p[r] = __builtin_amdgcn_exp2f(sB[r]);
        }
        lsB0 += ((p[0] + p[1]) + (p[2] + p[3])) + ((p[4] + p[5]) + (p[6] + p[7]));
        lsB1 += ((p[8] + p[9]) + (p[10] + p[11])) + ((p[12] + p[13]) + (p[14] + p[15]));
        unsigned pk[4][2];
        #pragma unroll
        for (int q4 = 0; q4 < 4; ++q4) {
          pk[q4][0] = cvtpk(p[q4 * 4 + 0], p[q4 * 4 + 1]);
          pk[q4][1] = cvtpk(p[q4 * 4 + 2], p[q4 * 4 + 3]);
        }
        __builtin_amdgcn_s_setprio(1);
        #pragma unroll
        for (int c2 = 0; c2 < 2; ++c2) {
          unsigned w0, w1, w2, w3;
          plswap(pk[2 * c2][0], pk[2 * c2 + 1][0], w0, w2);
          plswap(pk[2 * c2][1], pk[2 * c2 + 1][1], w1, w3);
          u32x4 pw = {w0, w1, w2, w3};
          u16x8 pf = __builtin_bit_cast(u16x8, pw);
          aB0 = mfma32(vf[c2 * 2 + 0], pf, aB0);
          aB1 = mfma32(vf[c2 * 2 + 1], pf, aB1);
        }
        __builtin_amdgcn_s_setprio(0);
      }
    };

    // ---- interior strips: s = w, w+4, ... < 2qp. Branchless, no mask. ----
    {
      const int num = 2 * qp - w;
      const int nfull = (num > 0) ? ((num + 3) >> 2) : 0;
      const unsigned char* pT = W + (size_t)(bh * 32 + (w >> 1)) * TILEB;
      for (int t = 0; t < nfull; ++t) {
        strip(pT, 0, true, false, false);
        pT += 2 * (size_t)TILEB;
      }
    }
    // ---- peeled diagonal strips (owner w = s & 3; parity matches w&1) ----
    {
      const int sD = 2 * qp;        // A-diagonal, B full
      if ((sD & 3) == w)
        strip(W + (size_t)(bh * 32 + (sD >> 1)) * TILEB, 32 * sD, true, true, false);
      const int sE = 2 * qp + 1;    // A inactive, B diagonal
      if ((sE & 3) == w)
        strip(W + (size_t)(bh * 32 + (sE >> 1)) * TILEB, 32 * sE, false, false, true);
    }

    // ---- sequential 3-round merge (both groups) through 16.9KB buffer ----
    float lsA = lsA0 + lsA1, lsB = lsB0 + lsB1;
    #pragma unroll
    for (int v = 1; v < 4; ++v) {
      __syncthreads();
      if (w == v) {
        float* m = &Mrg[lane][0];
        #pragma unroll
        for (int r = 0; r < 16; ++r) {
          m[r] = aA0[r]; m[16 + r] = aA1[r];
          m[33 + r] = aB0[r]; m[49 + r] = aB1[r];
        }
        m[32] = lsA; m[65] = lsB;
      }
      __syncthreads();
      if (w == 0) {
        const float* m = &Mrg[lane][0];
        #pragma unroll
        for (int r = 0; r < 16; ++r) {
          aA0[r] += m[r]; aA1[r] += m[16 + r];
          aB0[r] += m[33 + r]; aB1[r] += m[49 + r];
        }
        lsA += m[32]; lsB += m[65];
      }
    }
    if (w == 0) {
      lsA += __shfl_xor(lsA, 32);
      lsB += __shfl_xor(lsB, 32);
      const float invA = 1.0f / lsA;
      const float invB = 1.0f / lsB;
      float* opA = O + base + (size_t)(qmA + l31) * Dh;
      float* opB = O + base + (size_t)(qmB + l31) * Dh;
      #pragma unroll
      for (int r = 0; r < 16; ++r) {
        const int d = (r & 3) + 8 * (r >> 2) + 4 * h;
        opA[d]      = aA0[r] * invA;
        opA[32 + d] = aA1[r] * invA;
        opB[d]      = aB0[r] * invB;
        opB[32 + d] = aB1[r] * invB;
      }
    }

    if (!qcnt) break;   // static fallback: one job per block
  }
}

extern "C" void kernel_launch(void* const* d_in, const int* in_sizes, int n_in,
                              void* d_out, int out_size, void* d_ws, size_t ws_size,
                              hipStream_t stream) {
  const float* Q = (const float*)d_in[0];
  const float* K = (const float*)d_in[1];
  const float* V = (const float*)d_in[2];
  // d_in[3]: causal mask — static structure, handled in-kernel.
  float* O = (float*)d_out;
  unsigned char* W = (unsigned char*)d_ws;

  int* cnt = (ws_size >= CNT_OFF + 2048) ? (int*)(W + CNT_OFF) : nullptr;

  repack<<<dim3(1024), dim3(256), 0, stream>>>(K, V, W, cnt);
  fattn_fwd<<<dim3(cnt ? 640 : 1024), dim3(256), 0, stream>>>(Q, W, O, cnt);
}